// Round 3
// baseline (1128.685 us; speedup 1.0000x reference)
//
#include <hip/hip_runtime.h>

#define NN 100000
#define NE 1600000
#define HID 64
#define TXT 384
#define BATCH 1024

__device__ __forceinline__ ushort f2bf(float f) {
  unsigned u = __float_as_uint(f);
  unsigned r = (u + 0x7fffu + ((u >> 16) & 1u)) >> 16;  // round-to-nearest-even
  return (ushort)r;
}
__device__ __forceinline__ float bf2f(ushort u) {
  return __uint_as_float(((unsigned)u) << 16);
}

// ---------------- CSR build (unordered segment allocation, no scan) ----------
__global__ void k_count(const int* __restrict__ src, const int* __restrict__ dst,
                        int* __restrict__ cntf, int* __restrict__ cntr) {
  int e = blockIdx.x * blockDim.x + threadIdx.x;
  if (e >= NE) return;
  atomicAdd(&cntf[dst[e]], 1);   // forward graph: aggregate into dst
  atomicAdd(&cntr[src[e]], 1);   // reversed graph: aggregate into src
}

__global__ void k_alloc(const int* __restrict__ cntf, const int* __restrict__ cntr,
                        int* __restrict__ startf, int* __restrict__ curf,
                        int* __restrict__ startr, int* __restrict__ curr,
                        int* __restrict__ ctr) {
  int v = blockIdx.x * blockDim.x + threadIdx.x;
  if (v >= NN) return;
  int cf = cntf[v];
  int s = atomicAdd(&ctr[0], cf);
  startf[v] = s; curf[v] = s;
  int cr = cntr[v];
  int t = atomicAdd(&ctr[1], cr);
  startr[v] = t; curr[v] = t;
}

// packed (col, weight) per entry -> one 8B scattered store per direction
__global__ void k_fill(const int* __restrict__ src, const int* __restrict__ dst,
                       const float* __restrict__ w,
                       int* __restrict__ curf, int2* __restrict__ cvf,
                       int* __restrict__ curr, int2* __restrict__ cvr) {
  int e = blockIdx.x * blockDim.x + threadIdx.x;
  if (e >= NE) return;
  int s = src[e], d = dst[e];
  int wb = __float_as_int(w[e]);
  int p = atomicAdd(&curf[d], 1);
  cvf[p] = make_int2(s, wb);
  int q = atomicAdd(&curr[s], 1);
  cvr[q] = make_int2(d, wb);
}

// ---------------- weighted-mean aggregation: one wave per row, lane=feature --
// reads bf16 mirror of x (halves row-gather traffic)
__global__ void k_gather(const ushort* __restrict__ xb,
                         const int* __restrict__ start, const int* __restrict__ cnt,
                         const int2* __restrict__ cv,
                         float* __restrict__ out) {
  int wid = (blockIdx.x * blockDim.x + threadIdx.x) >> 6;
  int lane = threadIdx.x & 63;
  if (wid >= NN) return;
  int s = start[wid];
  int c = cnt[wid];
  int e = s + c;
  float acc = 0.f;
  int j = s;
  for (; j + 4 <= e; j += 4) {   // 4 independent gathers in flight
    int2 e0 = cv[j], e1 = cv[j + 1], e2 = cv[j + 2], e3 = cv[j + 3];
    float x0 = bf2f(xb[(size_t)e0.x * 64 + lane]);
    float x1 = bf2f(xb[(size_t)e1.x * 64 + lane]);
    float x2 = bf2f(xb[(size_t)e2.x * 64 + lane]);
    float x3 = bf2f(xb[(size_t)e3.x * 64 + lane]);
    acc += __int_as_float(e0.y) * x0;
    acc += __int_as_float(e1.y) * x1;
    acc += __int_as_float(e2.y) * x2;
    acc += __int_as_float(e3.y) * x3;
  }
  for (; j < e; ++j) {
    int2 ee = cv[j];
    acc += __int_as_float(ee.y) * bf2f(xb[(size_t)ee.x * 64 + lane]);
  }
  float inv = (c > 0) ? 1.0f / (float)c : 0.f;   // DGL mean; zero in-degree -> 0
  out[(size_t)wid * 64 + lane] = acc * inv;
}

// ---------------- encoder GEMM: [NN,384]@[384,64]+b -> x (+ bf16 mirror) -----
__launch_bounds__(256)
__global__ void k_enc(const float* __restrict__ T, const float* __restrict__ W,
                      const float* __restrict__ bias, float* __restrict__ x,
                      ushort* __restrict__ xb) {
  __shared__ float As[32][256];
  __shared__ float Bs[32][64];
  const int tid = threadIdx.x;
  const int row0 = blockIdx.x * 256;
  const int rg = tid >> 3, cg = tid & 7;
  float acc[8][8] = {};
  #pragma unroll 1
  for (int ch = 0; ch < 12; ++ch) {
    const int kc = ch * 32;
    const int arow = row0 + tid;
    if (arow < NN) {
      const float* p = T + (size_t)arow * TXT + kc;
      #pragma unroll
      for (int j = 0; j < 32; j += 4) {
        float4 v = *(const float4*)(p + j);
        As[j + 0][tid] = v.x; As[j + 1][tid] = v.y;
        As[j + 2][tid] = v.z; As[j + 3][tid] = v.w;
      }
    } else {
      #pragma unroll
      for (int j = 0; j < 32; ++j) As[j][tid] = 0.f;
    }
    {
      const int i = tid * 8, k = i >> 6, c = i & 63;
      float4 v0 = *(const float4*)(W + (kc + k) * 64 + c);
      float4 v1 = *(const float4*)(W + (kc + k) * 64 + c + 4);
      *(float4*)&Bs[k][c] = v0; *(float4*)&Bs[k][c + 4] = v1;
    }
    __syncthreads();
    #pragma unroll 4
    for (int k = 0; k < 32; ++k) {
      float4 a0 = *(const float4*)&As[k][rg * 8];
      float4 a1 = *(const float4*)&As[k][rg * 8 + 4];
      float4 b0 = *(const float4*)&Bs[k][cg * 8];
      float4 b1 = *(const float4*)&Bs[k][cg * 8 + 4];
      const float a[8] = {a0.x, a0.y, a0.z, a0.w, a1.x, a1.y, a1.z, a1.w};
      const float b[8] = {b0.x, b0.y, b0.z, b0.w, b1.x, b1.y, b1.z, b1.w};
      #pragma unroll
      for (int i = 0; i < 8; ++i)
        #pragma unroll
        for (int jj = 0; jj < 8; ++jj)
          acc[i][jj] = fmaf(a[i], b[jj], acc[i][jj]);
    }
    __syncthreads();
  }
  #pragma unroll
  for (int i = 0; i < 8; ++i) {
    const int row = row0 + rg * 8 + i;
    if (row >= NN) continue;
    float v[8];
    #pragma unroll
    for (int j = 0; j < 8; ++j) v[j] = acc[i][j] + bias[cg * 8 + j];
    float* xp = x + (size_t)row * 64 + cg * 8;
    *(float4*)xp = make_float4(v[0], v[1], v[2], v[3]);
    *(float4*)(xp + 4) = make_float4(v[4], v[5], v[6], v[7]);
    uint p4[4];
    #pragma unroll
    for (int j = 0; j < 4; ++j)
      p4[j] = (uint)f2bf(v[2 * j]) | ((uint)f2bf(v[2 * j + 1]) << 16);
    *(uint4*)(xb + (size_t)row * 64 + cg * 8) = make_uint4(p4[0], p4[1], p4[2], p4[3]);
  }
}

// ---------------- per-direction combine GEMM: [NN,128]@[128,64] --------------
// A = [x | n]; B = [Wself ; Wneigh].
// mode 0: n := relu(acc + bias)   (in-place over the neigh buffer, block-local rows)
// mode 1: x += yrel + relu(acc + bias); xb := bf16(x)   (skip connection fused;
//         yrel = relu(y_f) stored by the mode-0 pass — a DIFFERENT buffer than n)
__launch_bounds__(256)
__global__ void k_gemm(const float* __restrict__ A1, float* __restrict__ n,
                       const float* __restrict__ yrel,
                       const float* __restrict__ B1, const float* __restrict__ B2,
                       const float* __restrict__ bias,
                       float* __restrict__ x, ushort* __restrict__ xb, int mode) {
  __shared__ float As[32][256];
  __shared__ float Bs[32][64];
  const int tid = threadIdx.x;
  const int row0 = blockIdx.x * 256;
  const int rg = tid >> 3, cg = tid & 7;
  float acc[8][8] = {};
  #pragma unroll 1
  for (int ch = 0; ch < 4; ++ch) {
    const float* Asrc = (ch < 2) ? A1 : n;
    const float* Bsrc = (ch < 2) ? B1 : B2;
    const int kc = (ch & 1) * 32;
    const int arow = row0 + tid;
    if (arow < NN) {
      const float* p = Asrc + (size_t)arow * 64 + kc;
      #pragma unroll
      for (int j = 0; j < 32; j += 4) {
        float4 v = *(const float4*)(p + j);
        As[j + 0][tid] = v.x; As[j + 1][tid] = v.y;
        As[j + 2][tid] = v.z; As[j + 3][tid] = v.w;
      }
    } else {
      #pragma unroll
      for (int j = 0; j < 32; ++j) As[j][tid] = 0.f;
    }
    {
      const int i = tid * 8, k = i >> 6, c = i & 63;
      float4 v0 = *(const float4*)(Bsrc + (kc + k) * 64 + c);
      float4 v1 = *(const float4*)(Bsrc + (kc + k) * 64 + c + 4);
      *(float4*)&Bs[k][c] = v0; *(float4*)&Bs[k][c + 4] = v1;
    }
    __syncthreads();
    #pragma unroll 4
    for (int k = 0; k < 32; ++k) {
      float4 a0 = *(const float4*)&As[k][rg * 8];
      float4 a1 = *(const float4*)&As[k][rg * 8 + 4];
      float4 b0 = *(const float4*)&Bs[k][cg * 8];
      float4 b1 = *(const float4*)&Bs[k][cg * 8 + 4];
      const float a[8] = {a0.x, a0.y, a0.z, a0.w, a1.x, a1.y, a1.z, a1.w};
      const float b[8] = {b0.x, b0.y, b0.z, b0.w, b1.x, b1.y, b1.z, b1.w};
      #pragma unroll
      for (int i = 0; i < 8; ++i)
        #pragma unroll
        for (int jj = 0; jj < 8; ++jj)
          acc[i][jj] = fmaf(a[i], b[jj], acc[i][jj]);
    }
    __syncthreads();
  }
  #pragma unroll
  for (int i = 0; i < 8; ++i) {
    const int row = row0 + rg * 8 + i;
    if (row >= NN) continue;
    const int c0 = cg * 8;
    float vv[8];
    #pragma unroll
    for (int j = 0; j < 8; ++j) vv[j] = acc[i][j] + bias[c0 + j];
    if (mode == 0) {
      float* np = n + (size_t)row * 64 + c0;
      *(float4*)np = make_float4(fmaxf(vv[0], 0.f), fmaxf(vv[1], 0.f),
                                 fmaxf(vv[2], 0.f), fmaxf(vv[3], 0.f));
      *(float4*)(np + 4) = make_float4(fmaxf(vv[4], 0.f), fmaxf(vv[5], 0.f),
                                       fmaxf(vv[6], 0.f), fmaxf(vv[7], 0.f));
    } else {
      size_t base = (size_t)row * 64 + c0;
      float nv[8];
      float4 nf0 = *(const float4*)(yrel + base);
      float4 nf1 = *(const float4*)(yrel + base + 4);
      nv[0] = nf0.x; nv[1] = nf0.y; nv[2] = nf0.z; nv[3] = nf0.w;
      nv[4] = nf1.x; nv[5] = nf1.y; nv[6] = nf1.z; nv[7] = nf1.w;
      float xv[8];
      float4 x0 = *(const float4*)(x + base);
      float4 x1 = *(const float4*)(x + base + 4);
      xv[0] = x0.x; xv[1] = x0.y; xv[2] = x0.z; xv[3] = x0.w;
      xv[4] = x1.x; xv[5] = x1.y; xv[6] = x1.z; xv[7] = x1.w;
      float o[8];
      #pragma unroll
      for (int j = 0; j < 8; ++j) o[j] = xv[j] + nv[j] + fmaxf(vv[j], 0.f);
      *(float4*)(x + base) = make_float4(o[0], o[1], o[2], o[3]);
      *(float4*)(x + base + 4) = make_float4(o[4], o[5], o[6], o[7]);
      uint p4[4];
      #pragma unroll
      for (int j = 0; j < 4; ++j)
        p4[j] = (uint)f2bf(o[2 * j]) | ((uint)f2bf(o[2 * j + 1]) << 16);
      *(uint4*)(xb + base) = make_uint4(p4[0], p4[1], p4[2], p4[3]);
    }
  }
}

// ---------------- output gather + L2 normalize -------------------------------
__global__ void k_out(const float* __restrict__ x, const int* __restrict__ ids,
                      float* __restrict__ out) {
  int b = (blockIdx.x * blockDim.x + threadIdx.x) >> 6;
  int lane = threadIdx.x & 63;
  if (b >= BATCH) return;
  int row = ids[b];
  float v = x[(size_t)row * 64 + lane];
  float s = v * v;
  #pragma unroll
  for (int m = 1; m < 64; m <<= 1) s += __shfl_xor(s, m);
  out[b * 64 + lane] = v / sqrtf(s);
}

extern "C" void kernel_launch(void* const* d_in, const int* in_sizes, int n_in,
                              void* d_out, int out_size, void* d_ws, size_t ws_size,
                              hipStream_t stream) {
  const float* text = (const float*)d_in[0];
  const float* wts  = (const float*)d_in[1];
  const float* Wenc = (const float*)d_in[2];
  const float* benc = (const float*)d_in[3];
  const float* Wsf  = (const float*)d_in[4];
  const float* Wnf  = (const float*)d_in[5];
  const float* bf   = (const float*)d_in[6];
  const float* Wsr  = (const float*)d_in[7];
  const float* Wnr  = (const float*)d_in[8];
  const float* br   = (const float*)d_in[9];
  const int*   src  = (const int*)d_in[10];
  const int*   dst  = (const int*)d_in[11];
  const int*   ids  = (const int*)d_in[12];
  float* out = (float*)d_out;

  char* ws = (char*)d_ws;
  size_t o = 0;
  auto alloc = [&](size_t f32elems) {
    void* p = ws + o;
    o += f32elems * 4;
    o = (o + 255) & ~(size_t)255;
    return p;
  };
  float*  x   = (float*)alloc((size_t)NN * 64);
  float*  nf  = (float*)alloc((size_t)NN * 64);
  float*  nr  = (float*)alloc((size_t)NN * 64);
  ushort* xb  = (ushort*)alloc((size_t)NN * 32);   // bf16 mirror of x
  int2*   cvf = (int2*)alloc((size_t)NE * 2);      // packed (col, weight)
  int2*   cvr = (int2*)alloc((size_t)NE * 2);
  // ---- zero region start (one memset covers cntf..ctr) ----
  int* cntf = (int*)alloc(NN);
  int* cntr = (int*)alloc(NN);
  int* ctr  = (int*)alloc(64);
  // ---- zero region end ----
  int* startf = (int*)alloc(NN);
  int* curf   = (int*)alloc(NN);
  int* startr = (int*)alloc(NN);
  int* curr   = (int*)alloc(NN);

  size_t zbytes = (size_t)((char*)startf - (char*)cntf);
  hipMemsetAsync(cntf, 0, zbytes, stream);

  const int EB = (NE + 255) / 256;
  const int VB = (NN + 255) / 256;

  k_count<<<EB, 256, 0, stream>>>(src, dst, cntf, cntr);
  k_alloc<<<VB, 256, 0, stream>>>(cntf, cntr, startf, curf, startr, curr, ctr);
  k_fill<<<EB, 256, 0, stream>>>(src, dst, wts, curf, cvf, curr, cvr);
  k_enc<<<VB, 256, 0, stream>>>(text, Wenc, benc, x, xb);

  const int GB = ((size_t)NN * 64 + 255) / 256;  // 1 wave per row
  for (int l = 0; l < 2; ++l) {
    const float* Wsf_l = Wsf + l * HID * HID;
    const float* Wnf_l = Wnf + l * HID * HID;
    const float* Wsr_l = Wsr + l * HID * HID;
    const float* Wnr_l = Wnr + l * HID * HID;
    const float* bf_l  = bf + l * HID;
    const float* br_l  = br + l * HID;
    k_gather<<<GB, 256, 0, stream>>>(xb, startf, cntf, cvf, nf);
    k_gather<<<GB, 256, 0, stream>>>(xb, startr, cntr, cvr, nr);
    // mode 0: nf := relu(y_f)
    k_gemm<<<VB, 256, 0, stream>>>(x, nf, nf, Wsf_l, Wnf_l, bf_l, x, xb, 0);
    // mode 1: x += nf (=relu(y_f)) + relu(y_r)
    k_gemm<<<VB, 256, 0, stream>>>(x, nr, nf, Wsr_l, Wnr_l, br_l, x, xb, 1);
  }
  k_out<<<(BATCH * 64) / 256, 256, 0, stream>>>(x, ids, out);
}